// Round 1
// baseline (429.546 us; speedup 1.0000x reference)
//
#include <hip/hip_runtime.h>
#include <math.h>

// B=8, S=512, D=1024, P=128, H=8 ; rows = B*S = 4096
__device__ __forceinline__ float sigmoidf_(float x){ return 1.f/(1.f+expf(-x)); }
__device__ __forceinline__ float geluf_(float x){ return 0.5f*x*(1.f+erff(x*0.70710678118654752f)); }

// ---------- pack Wa|Wp -> Wcat [1024][256], ba|bp -> bcat[256] ----------
__global__ __launch_bounds__(256) void pack_kernel(
    const float* __restrict__ Wa, const float* __restrict__ Wp,
    const float* __restrict__ ba, const float* __restrict__ bp,
    float* __restrict__ Wcat, float* __restrict__ bcat)
{
  int idx = blockIdx.x*256 + threadIdx.x;     // 0..262143
  int k = idx >> 8, c = idx & 255;
  Wcat[idx] = (c < 128) ? Wa[k*128 + c] : Wp[k*128 + (c-128)];
  if (idx < 256) bcat[idx] = (idx < 128) ? ba[idx] : bp[idx-128];
}

// ---------- generic fp32 GEMM: C = epi(A@B + bias [+resid]) ----------
// 64x64 tile, BK=16, 256 threads, 4x4 per thread. batched via blockIdx.z.
// EPI: 0 = +bias ; 1 = gelu(+bias) ; 2 = +bias+resid
template<int EPI>
__global__ __launch_bounds__(256) void gemm_k(
    const float* __restrict__ A, const float* __restrict__ Bm,
    const float* __restrict__ bias, const float* __restrict__ resid,
    float* __restrict__ C, int M, int N, int K,
    long sA, long sB, long sBias, long sC)
{
  int z = blockIdx.z;
  A += (long)z*sA; Bm += (long)z*sB; bias += (long)z*sBias; C += (long)z*sC;
  __shared__ float As[16][64];   // [k][m] (transposed store)
  __shared__ float Bs[16][64];   // [k][n]
  const int tid = threadIdx.x;
  const int tx = tid & 15, ty = tid >> 4;
  const int row0 = blockIdx.x * 64, col0 = blockIdx.y * 64;
  const int ar = tid >> 2, akc = (tid & 3) << 2;
  const int bk = tid >> 4, bnc = (tid & 15) << 2;
  float acc[4][4] = {};
  for (int k0 = 0; k0 < K; k0 += 16) {
    float4 av = *(const float4*)(A + (long)(row0+ar)*K + k0 + akc);
    float4 bv = *(const float4*)(Bm + (long)(k0+bk)*N + col0 + bnc);
    As[akc+0][ar]=av.x; As[akc+1][ar]=av.y; As[akc+2][ar]=av.z; As[akc+3][ar]=av.w;
    *(float4*)(&Bs[bk][bnc]) = bv;
    __syncthreads();
    #pragma unroll
    for (int k=0;k<16;++k){
      float4 a4 = *(const float4*)(&As[k][ty<<2]);
      float4 b4 = *(const float4*)(&Bs[k][tx<<2]);
      const float a[4]={a4.x,a4.y,a4.z,a4.w}, b[4]={b4.x,b4.y,b4.z,b4.w};
      #pragma unroll
      for (int i=0;i<4;++i)
        #pragma unroll
        for (int j=0;j<4;++j) acc[i][j] = fmaf(a[i], b[j], acc[i][j]);
    }
    __syncthreads();
  }
  #pragma unroll
  for (int i=0;i<4;++i){
    int r = row0 + (ty<<2) + i;
    int c = col0 + (tx<<2);
    float4 o; float* po = &o.x;
    #pragma unroll
    for (int j=0;j<4;++j){
      float v = acc[i][j] + bias[c+j];
      if (EPI==1) v = geluf_(v);
      if (EPI==2) v += resid[(long)r*N + c + j];
      po[j] = v;
    }
    *(float4*)(C + (long)r*N + c) = o;
  }
}

// ---------- real = tanh(a)*cos(2pi*sigmoid(ph)); xn = LN_P(real)*g1+bt1 ----------
// one wave per row (2 elems/lane), 4 rows/block
__global__ __launch_bounds__(256) void encode_ln_kernel(
    const float* __restrict__ E, const float* __restrict__ g1, const float* __restrict__ bt1,
    float* __restrict__ realp, float* __restrict__ xnp)
{
  int wv = threadIdx.x >> 6, lane = threadIdx.x & 63;
  long row = (long)blockIdx.x*4 + wv;         // 0..4095
  const float* e = E + row*256;
  int p = lane*2;
  float2 a = *(const float2*)(e + p);
  float2 f = *(const float2*)(e + 128 + p);
  const float TWO_PI = 6.28318530717958647692f;
  float r0 = tanhf(a.x) * cosf(TWO_PI * sigmoidf_(f.x));
  float r1 = tanhf(a.y) * cosf(TWO_PI * sigmoidf_(f.y));
  float s = r0+r1, ss = r0*r0 + r1*r1;
  #pragma unroll
  for (int m=1;m<64;m<<=1){ s += __shfl_xor(s,m,64); ss += __shfl_xor(ss,m,64); }
  float mean = s * (1.f/128.f);
  float var  = ss * (1.f/128.f) - mean*mean;
  float inv  = rsqrtf(var + 1e-5f);
  float x0 = (r0-mean)*inv*g1[p]   + bt1[p];
  float x1 = (r1-mean)*inv*g1[p+1] + bt1[p+1];
  *(float2*)(realp + row*128 + p) = make_float2(r0,r1);
  *(float2*)(xnp   + row*128 + p) = make_float2(x0,x1);
}

// ---------- per-channel autocorr (lags -256..255) -> sigmoid -> sig[h,b,s,p] ----------
// block = 4 waves; wave w owns channel (h,b,p4*4+w). Signal zero-padded in LDS,
// physical index i + (i>>3) (pad word every 8) -> stride-8 window reads hit all banks.
__global__ __launch_bounds__(256) void autocorr_kernel(
    const float* __restrict__ t, float* __restrict__ sig)
{
  __shared__ float vp[4][1152];               // 1024 logical + 128 pad
  int bidx = blockIdx.x;                      // 0..2047
  int p4 = bidx & 31; int hb = bidx >> 5; int b = hb & 7, h = hb >> 3;
  float* vflat = &vp[0][0];
  for (int i = threadIdx.x; i < 4*1152; i += 256) vflat[i] = 0.f;
  __syncthreads();
  const float* tp = t + ((long)(h*4096 + b*512))*128 + p4*4;
  for (int idx = threadIdx.x; idx < 2048; idx += 256) {
    int s = idx >> 2, c = idx & 3;
    int li = 256 + s;
    vp[c][li + (li>>3)] = tp[(long)s*128 + c];
  }
  __syncthreads();
  int wv = threadIdx.x >> 6, lane = threadIdx.x & 63;
  const float* V = vp[wv];
  int s0 = lane*8;                            // 8 consecutive output lags per lane
  float acc[8] = {0,0,0,0,0,0,0,0};
  float w[8];
  #pragma unroll
  for (int u=0;u<8;++u){ int li=s0+u; w[u] = V[li + (li>>3)]; }
  for (int kb=0; kb<512; kb+=8) {
    float nw[8];
    #pragma unroll
    for (int u=0;u<8;++u){ int li = kb+8+s0+u; nw[u] = V[li + (li>>3)]; }
    #pragma unroll
    for (int u=0;u<8;++u){
      int lb = kb+u+256;
      float aa = V[lb + (lb>>3)];             // wave-uniform -> broadcast
      #pragma unroll
      for (int j=0;j<8;++j){
        float wlj = (u+j<8) ? w[u+j] : nw[u+j-8];
        acc[j] = fmaf(aa, wlj, acc[j]);
      }
    }
    #pragma unroll
    for (int u=0;u<8;++u) w[u]=nw[u];
  }
  float* sp = sig + ((long)(h*4096 + b*512) + s0)*128 + p4*4 + wv;
  #pragma unroll
  for (int j=0;j<8;++j) sp[(long)j*128] = sigmoidf_(acc[j]);
}

// ---------- gated = real*sig ; y[b,s,h*128+p] = LN_P(gated)*g2+bt2 ----------
__global__ __launch_bounds__(256) void gate_ln_kernel(
    const float* __restrict__ realp, const float* __restrict__ sig,
    const float* __restrict__ g2, const float* __restrict__ bt2,
    float* __restrict__ y)
{
  int wv = threadIdx.x >> 6, lane = threadIdx.x & 63;
  long r = (long)blockIdx.x*4 + wv;           // (h,b,s) row, 0..32767
  int h = (int)(r >> 12);
  long rem = r & 4095;                        // b*512+s
  int p = lane*2;
  float2 rv = *(const float2*)(realp + rem*128 + p);
  float2 sv = *(const float2*)(sig + r*128 + p);
  float a0 = rv.x*sv.x, a1 = rv.y*sv.y;
  float s = a0+a1, ss = a0*a0+a1*a1;
  #pragma unroll
  for (int m=1;m<64;m<<=1){ s += __shfl_xor(s,m,64); ss += __shfl_xor(ss,m,64); }
  float mean = s*(1.f/128.f);
  float var  = ss*(1.f/128.f) - mean*mean;
  float inv  = rsqrtf(var+1e-5f);
  float y0 = (a0-mean)*inv*g2[p]   + bt2[p];
  float y1 = (a1-mean)*inv*g2[p+1] + bt2[p+1];
  *(float2*)(y + rem*1024 + h*128 + p) = make_float2(y0,y1);
}

extern "C" void kernel_launch(void* const* d_in, const int* in_sizes, int n_in,
                              void* d_out, int out_size, void* d_ws, size_t ws_size,
                              hipStream_t stream)
{
  const float* x   = (const float*)d_in[0];
  const float* Wa  = (const float*)d_in[1];
  const float* ba  = (const float*)d_in[2];
  const float* Wp  = (const float*)d_in[3];
  const float* bp  = (const float*)d_in[4];
  const float* g1  = (const float*)d_in[5];
  const float* bt1 = (const float*)d_in[6];
  const float* W1  = (const float*)d_in[7];
  const float* bh1 = (const float*)d_in[8];
  const float* W2  = (const float*)d_in[9];
  const float* bh2 = (const float*)d_in[10];
  const float* g2  = (const float*)d_in[11];
  const float* bt2 = (const float*)d_in[12];
  const float* Wo  = (const float*)d_in[13];
  const float* bo  = (const float*)d_in[14];
  float* ws = (float*)d_ws;
  float* Wcat  = ws + 0;          // 262144
  float* bcat  = ws + 262144;     // 256
  float* E     = ws + 262400;     // 4096*256
  float* realp = ws + 1310976;    // 4096*128
  float* xnp   = ws + 1835264;    // 4096*128
  float* hid   = ws + 2359552;    // 8*4096*256
  float* sigb  = hid;             // alias: hid dead after t-gemm (4M <= 8M floats)
  float* tbuf  = ws + 10748160;   // 8*4096*128
  float* ybuf  = tbuf;            // alias: t dead after autocorr
  float* out   = (float*)d_out;

  pack_kernel<<<1024,256,0,stream>>>(Wa,Wp,ba,bp,Wcat,bcat);
  // E = x @ [Wa|Wp] + [ba|bp]
  gemm_k<0><<<dim3(64,4,1),256,0,stream>>>(x,Wcat,bcat,nullptr,E, 4096,256,1024, 0,0,0,0);
  encode_ln_kernel<<<1024,256,0,stream>>>(E,g1,bt1,realp,xnp);
  // hid[h] = gelu(xn @ W1[h] + bh1[h])
  gemm_k<1><<<dim3(64,4,8),256,0,stream>>>(xnp,W1,bh1,nullptr,hid,
                                           4096,256,128, 0, 128*256, 256, (long)4096*256);
  // t[h] = hid[h] @ W2[h] + bh2[h]
  gemm_k<0><<<dim3(64,2,8),256,0,stream>>>(hid,W2,bh2,nullptr,tbuf,
                                           4096,128,256, (long)4096*256, 256*128, 128, (long)4096*128);
  autocorr_kernel<<<2048,256,0,stream>>>(tbuf, sigb);
  gate_ln_kernel<<<8192,256,0,stream>>>(realp, sigb, g2, bt2, ybuf);
  // out = y @ Wo + bo + x
  gemm_k<2><<<dim3(64,16,1),256,0,stream>>>(ybuf,Wo,bo,x,out, 4096,1024,1024, 0,0,0,0);
}

// Round 3
// 288.396 us; speedup vs baseline: 1.4894x; 1.4894x over previous
//
#include <hip/hip_runtime.h>
#include <math.h>

// B=8, S=512, D=1024, P=128, H=8 ; rows = B*S = 4096
typedef __attribute__((ext_vector_type(8))) short bf16x8_t;
typedef __attribute__((ext_vector_type(4))) float f32x4_t;

__device__ __forceinline__ float sigmoidf_(float x){ return 1.f/(1.f+expf(-x)); }
__device__ __forceinline__ float geluf_(float x){ return 0.5f*x*(1.f+erff(x*0.70710678118654752f)); }
__device__ __forceinline__ unsigned short f2bf(float x){
  unsigned int u = __float_as_uint(x);
  return (unsigned short)((u + 0x7fffu + ((u>>16)&1u)) >> 16);
}
__device__ __forceinline__ float bf2f(unsigned short h){
  return __uint_as_float(((unsigned int)h)<<16);
}
__device__ __forceinline__ bf16x8_t ldfrag(const unsigned short* p){
  union { bf16x8_t v; uint2 q[2]; } u;
  u.q[0] = *(const uint2*)p; u.q[1] = *(const uint2*)(p+4); return u.v;
}

// ---------- bias concat ----------
__global__ __launch_bounds__(256) void bias_pack(const float* __restrict__ ba,
    const float* __restrict__ bp, float* __restrict__ bcat){
  int t = threadIdx.x; bcat[t] = (t<128)? ba[t] : bp[t-128];
}

// ---------- transpose + split fp32 -> (hi,lo) bf16 ; dst[c][r] = src[r][c] ----------
__global__ __launch_bounds__(256) void transpose_split(
    const float* __restrict__ src, unsigned short* __restrict__ dhi,
    unsigned short* __restrict__ dlo, int R, int C)
{
  long zoff = (long)blockIdx.z * R * C;
  src += zoff; dhi += zoff; dlo += zoff;
  __shared__ float tile[32][33];
  int c0 = blockIdx.x*32, r0 = blockIdx.y*32;
  int j = threadIdx.x & 31, i0 = threadIdx.x >> 5;
  #pragma unroll
  for (int ii=0; ii<4; ++ii){ int i = i0 + ii*8;
    tile[i][j] = src[(long)(r0+i)*C + c0 + j]; }
  __syncthreads();
  #pragma unroll
  for (int ii=0; ii<4; ++ii){ int i = i0 + ii*8;
    float v = tile[j][i];
    unsigned short h = f2bf(v);
    dhi[(long)(c0+i)*R + r0 + j] = h;
    dlo[(long)(c0+i)*R + r0 + j] = f2bf(v - bf2f(h));
  }
}

// ---------- split-bf16 MFMA GEMM: C = epi(A@B + bias [+resid]) ----------
// A fp32 [M][K] (split on the fly); B pre-split transposed [N][K] hi/lo bf16.
// block tile 64x128, BK=64, 4 waves (2x2), wave tile 32x64 via 16x16x32 MFMA.
// EPI: 0 = +bias ; 1 = gelu(+bias) ; 2 = +bias+resid
template<int EPI>
__global__ __launch_bounds__(256) void gemm_mfma(
    const float* __restrict__ A, const unsigned short* __restrict__ Bhi,
    const unsigned short* __restrict__ Blo,
    const float* __restrict__ bias, const float* __restrict__ resid,
    float* __restrict__ C, int M, int N, int K,
    long sA, long sB, long sBias, long sC)
{
  int z = blockIdx.z;
  A += z*sA; Bhi += z*sB; Blo += z*sB; bias += z*sBias; C += z*sC;
  __shared__ unsigned short As_hi[64][68], As_lo[64][68];
  __shared__ unsigned short Bs_hi[128][68], Bs_lo[128][68];
  const int tid = threadIdx.x;
  const int lane = tid & 63, wv = tid >> 6;
  const int wr = wv >> 1, wc = wv & 1;
  const int mw = wr*32, nw = wc*64;
  const int la = lane & 15, kg = (lane >> 4) << 3;
  const int m0 = blockIdx.x * 64, n0 = blockIdx.y * 128;

  f32x4_t acc[2][4];
  #pragma unroll
  for (int i=0;i<2;++i)
    #pragma unroll
    for (int j=0;j<4;++j) acc[i][j] = (f32x4_t){0.f,0.f,0.f,0.f};

  for (int k0 = 0; k0 < K; k0 += 64) {
    float4 av[4]; uint4 bh4[4], bl4[4];
    #pragma unroll
    for (int r=0;r<4;++r){
      int ia = tid + r*256;
      av[r] = *(const float4*)(A + (long)(m0 + (ia>>4))*K + k0 + ((ia&15)<<2));
      int ib = tid + r*256;
      long bo = (long)(n0 + (ib>>3))*K + k0 + ((ib&7)<<3);
      bh4[r] = *(const uint4*)(Bhi + bo);
      bl4[r] = *(const uint4*)(Blo + bo);
    }
    __syncthreads();
    #pragma unroll
    for (int r=0;r<4;++r){
      int ia = tid + r*256;
      int arow = ia>>4, akc = (ia&15)<<2;
      float4 v = av[r];
      unsigned short h0=f2bf(v.x),h1=f2bf(v.y),h2=f2bf(v.z),h3=f2bf(v.w);
      uint2 whi; whi.x = (unsigned)h0 | ((unsigned)h1<<16); whi.y = (unsigned)h2 | ((unsigned)h3<<16);
      *(uint2*)&As_hi[arow][akc] = whi;
      unsigned short l0=f2bf(v.x-bf2f(h0)),l1=f2bf(v.y-bf2f(h1)),
                     l2=f2bf(v.z-bf2f(h2)),l3=f2bf(v.w-bf2f(h3));
      uint2 wlo; wlo.x = (unsigned)l0 | ((unsigned)l1<<16); wlo.y = (unsigned)l2 | ((unsigned)l3<<16);
      *(uint2*)&As_lo[arow][akc] = wlo;
      int ib = tid + r*256;
      int bn = ib>>3, bkc = (ib&7)<<3;
      uint2 t0; t0.x = bh4[r].x; t0.y = bh4[r].y;
      uint2 t1; t1.x = bh4[r].z; t1.y = bh4[r].w;
      *(uint2*)&Bs_hi[bn][bkc]   = t0;
      *(uint2*)&Bs_hi[bn][bkc+4] = t1;
      uint2 t2; t2.x = bl4[r].x; t2.y = bl4[r].y;
      uint2 t3; t3.x = bl4[r].z; t3.y = bl4[r].w;
      *(uint2*)&Bs_lo[bn][bkc]   = t2;
      *(uint2*)&Bs_lo[bn][bkc+4] = t3;
    }
    __syncthreads();
    #pragma unroll
    for (int kk=0; kk<2; ++kk){
      bf16x8_t ah[2], al[2], bh[4], bl[4];
      #pragma unroll
      for (int mf=0; mf<2; ++mf){
        ah[mf] = ldfrag(&As_hi[mw + mf*16 + la][kk*32 + kg]);
        al[mf] = ldfrag(&As_lo[mw + mf*16 + la][kk*32 + kg]);
      }
      #pragma unroll
      for (int nf=0; nf<4; ++nf){
        bh[nf] = ldfrag(&Bs_hi[nw + nf*16 + la][kk*32 + kg]);
        bl[nf] = ldfrag(&Bs_lo[nw + nf*16 + la][kk*32 + kg]);
      }
      #pragma unroll
      for (int mf=0; mf<2; ++mf)
        #pragma unroll
        for (int nf=0; nf<4; ++nf){
          acc[mf][nf] = __builtin_amdgcn_mfma_f32_16x16x32_bf16(ah[mf], bh[nf], acc[mf][nf], 0,0,0);
          acc[mf][nf] = __builtin_amdgcn_mfma_f32_16x16x32_bf16(ah[mf], bl[nf], acc[mf][nf], 0,0,0);
          acc[mf][nf] = __builtin_amdgcn_mfma_f32_16x16x32_bf16(al[mf], bh[nf], acc[mf][nf], 0,0,0);
        }
    }
  }
  // epilogue: C/D layout col=lane&15, row=(lane>>4)*4+reg
  #pragma unroll
  for (int mf=0; mf<2; ++mf){
    int grow0 = m0 + mw + mf*16 + ((lane>>4)<<2);
    #pragma unroll
    for (int nf=0; nf<4; ++nf){
      int gcol = n0 + nw + nf*16 + la;
      float bsv = bias[gcol];
      #pragma unroll
      for (int r=0;r<4;++r){
        int grow = grow0 + r;
        float v = acc[mf][nf][r] + bsv;
        if (EPI==1) v = geluf_(v);
        if (EPI==2) v += resid[(long)grow*N + gcol];
        C[(long)grow*N + gcol] = v;
      }
    }
  }
}

// ---------- real = tanh(a)*cos(2pi*sigmoid(ph)); xn = LN_P(real)*g1+bt1 ----------
__global__ __launch_bounds__(256) void encode_ln_kernel(
    const float* __restrict__ E, const float* __restrict__ g1, const float* __restrict__ bt1,
    float* __restrict__ realp, float* __restrict__ xnp)
{
  int wv = threadIdx.x >> 6, lane = threadIdx.x & 63;
  long row = (long)blockIdx.x*4 + wv;         // 0..4095
  const float* e = E + row*256;
  int p = lane*2;
  float2 a = *(const float2*)(e + p);
  float2 f = *(const float2*)(e + 128 + p);
  const float TWO_PI = 6.28318530717958647692f;
  float r0 = tanhf(a.x) * cosf(TWO_PI * sigmoidf_(f.x));
  float r1 = tanhf(a.y) * cosf(TWO_PI * sigmoidf_(f.y));
  float s = r0+r1, ss = r0*r0 + r1*r1;
  #pragma unroll
  for (int m=1;m<64;m<<=1){ s += __shfl_xor(s,m,64); ss += __shfl_xor(ss,m,64); }
  float mean = s * (1.f/128.f);
  float var  = ss * (1.f/128.f) - mean*mean;
  float inv  = rsqrtf(var + 1e-5f);
  float x0 = (r0-mean)*inv*g1[p]   + bt1[p];
  float x1 = (r1-mean)*inv*g1[p+1] + bt1[p+1];
  *(float2*)(realp + row*128 + p) = make_float2(r0,r1);
  *(float2*)(xnp   + row*128 + p) = make_float2(x0,x1);
}

// ---------- per-channel autocorr (lags -256..255) -> sigmoid -> sig[h,b,s,p] ----------
// physical index i + 2*(i>>3): 2-float pad every 8 -> float2 loads stay aligned.
__global__ __launch_bounds__(256) void autocorr_kernel(
    const float* __restrict__ t, float* __restrict__ sig)
{
  __shared__ float vp[4][1280];               // 1024 logical + 2 pad per 8
  int bidx = blockIdx.x;                      // 0..2047
  int p4 = bidx & 31; int hb = bidx >> 5; int b = hb & 7, h = hb >> 3;
  float* vflat = &vp[0][0];
  for (int i = threadIdx.x; i < 4*1280; i += 256) vflat[i] = 0.f;
  __syncthreads();
  const float* tp = t + ((long)(h*4096 + b*512))*128 + p4*4;
  for (int idx = threadIdx.x; idx < 2048; idx += 256) {
    int s = idx >> 2, c = idx & 3;
    int li = 256 + s;
    vp[c][li + ((li>>3)<<1)] = tp[(long)s*128 + c];
  }
  __syncthreads();
  int wv = threadIdx.x >> 6, lane = threadIdx.x & 63;
  const float* V = vp[wv];
  int s0 = lane*8;                            // 8 consecutive output lags per lane
  float acc[8] = {0,0,0,0,0,0,0,0};
  float w[8], ba_[8];
  #pragma unroll
  for (int u=0;u<8;u+=2){ int li=s0+u; *(float2*)&w[u] = *(const float2*)&V[li + ((li>>3)<<1)]; }
  for (int kb=0; kb<512; kb+=8) {
    float nw[8];
    int nb0 = kb+8+s0;
    #pragma unroll
    for (int u=0;u<8;u+=2){ int li = nb0+u; *(float2*)&nw[u] = *(const float2*)&V[li + ((li>>3)<<1)]; }
    int lb0 = kb+256;
    #pragma unroll
    for (int u=0;u<8;u+=2){ int li = lb0+u; *(float2*)&ba_[u] = *(const float2*)&V[li + ((li>>3)<<1)]; }
    #pragma unroll
    for (int u=0;u<8;++u){
      float aa = ba_[u];
      #pragma unroll
      for (int j=0;j<8;++j){
        float wlj = (u+j<8) ? w[u+j] : nw[u+j-8];
        acc[j] = fmaf(aa, wlj, acc[j]);
      }
    }
    #pragma unroll
    for (int u=0;u<8;++u) w[u]=nw[u];
  }
  float* sp = sig + ((long)(h*4096 + b*512) + s0)*128 + p4*4 + wv;
  #pragma unroll
  for (int j=0;j<8;++j) sp[(long)j*128] = sigmoidf_(acc[j]);
}

// ---------- gated = real*sig ; y[b,s,h*128+p] = LN_P(gated)*g2+bt2 ----------
__global__ __launch_bounds__(256) void gate_ln_kernel(
    const float* __restrict__ realp, const float* __restrict__ sig,
    const float* __restrict__ g2, const float* __restrict__ bt2,
    float* __restrict__ y)
{
  int wv = threadIdx.x >> 6, lane = threadIdx.x & 63;
  long r = (long)blockIdx.x*4 + wv;           // (h,b,s) row, 0..32767
  int h = (int)(r >> 12);
  long rem = r & 4095;                        // b*512+s
  int p = lane*2;
  float2 rv = *(const float2*)(realp + rem*128 + p);
  float2 sv = *(const float2*)(sig + r*128 + p);
  float a0 = rv.x*sv.x, a1 = rv.y*sv.y;
  float s = a0+a1, ss = a0*a0+a1*a1;
  #pragma unroll
  for (int m=1;m<64;m<<=1){ s += __shfl_xor(s,m,64); ss += __shfl_xor(ss,m,64); }
  float mean = s*(1.f/128.f);
  float var  = ss*(1.f/128.f) - mean*mean;
  float inv  = rsqrtf(var+1e-5f);
  float y0 = (a0-mean)*inv*g2[p]   + bt2[p];
  float y1 = (a1-mean)*inv*g2[p+1] + bt2[p+1];
  *(float2*)(y + rem*1024 + h*128 + p) = make_float2(y0,y1);
}

extern "C" void kernel_launch(void* const* d_in, const int* in_sizes, int n_in,
                              void* d_out, int out_size, void* d_ws, size_t ws_size,
                              hipStream_t stream)
{
  const float* x   = (const float*)d_in[0];
  const float* Wa  = (const float*)d_in[1];
  const float* ba  = (const float*)d_in[2];
  const float* Wp  = (const float*)d_in[3];
  const float* bp  = (const float*)d_in[4];
  const float* g1  = (const float*)d_in[5];
  const float* bt1 = (const float*)d_in[6];
  const float* W1  = (const float*)d_in[7];
  const float* bh1 = (const float*)d_in[8];
  const float* W2  = (const float*)d_in[9];
  const float* bh2 = (const float*)d_in[10];
  const float* g2  = (const float*)d_in[11];
  const float* bt2 = (const float*)d_in[12];
  const float* Wo  = (const float*)d_in[13];
  const float* bo  = (const float*)d_in[14];

  char* p = (char*)d_ws;
  auto alloc = [&](size_t bytes)->char*{ char* r = p; p += (bytes + 255) & ~(size_t)255; return r; };
  float* bcat = (float*)alloc(256*4);
  unsigned short* WcatT_hi = (unsigned short*)alloc(256*1024*2);
  unsigned short* WcatT_lo = (unsigned short*)alloc(256*1024*2);
  unsigned short* W1T_hi   = (unsigned short*)alloc(8*256*128*2);
  unsigned short* W1T_lo   = (unsigned short*)alloc(8*256*128*2);
  unsigned short* W2T_hi   = (unsigned short*)alloc(8*128*256*2);
  unsigned short* W2T_lo   = (unsigned short*)alloc(8*128*256*2);
  unsigned short* WoT_hi   = (unsigned short*)alloc(1024*1024*2);
  unsigned short* WoT_lo   = (unsigned short*)alloc(1024*1024*2);
  float* E     = (float*)alloc((size_t)4096*256*4);
  float* realp = (float*)alloc((size_t)4096*128*4);
  float* xnp   = (float*)alloc((size_t)4096*128*4);
  float* hid   = (float*)alloc((size_t)8*4096*256*4);
  float* tbuf  = (float*)alloc((size_t)8*4096*128*4);
  float* sigb  = hid;    // hid dead after t-gemm
  float* ybuf  = tbuf;   // tbuf dead after autocorr
  float* out   = (float*)d_out;

  bias_pack<<<1,256,0,stream>>>(ba,bp,bcat);
  transpose_split<<<dim3(4,32,1),256,0,stream>>>(Wa, WcatT_hi, WcatT_lo, 1024,128);
  transpose_split<<<dim3(4,32,1),256,0,stream>>>(Wp, WcatT_hi+131072, WcatT_lo+131072, 1024,128);
  transpose_split<<<dim3(8,4,8),256,0,stream>>>(W1, W1T_hi, W1T_lo, 128,256);
  transpose_split<<<dim3(4,8,8),256,0,stream>>>(W2, W2T_hi, W2T_lo, 256,128);
  transpose_split<<<dim3(32,32,1),256,0,stream>>>(Wo, WoT_hi, WoT_lo, 1024,1024);

  // E = x @ [Wa|Wp] + [ba|bp]
  gemm_mfma<0><<<dim3(64,2,1),256,0,stream>>>(x, WcatT_hi, WcatT_lo, bcat, nullptr, E,
                                              4096,256,1024, 0,0,0,0);
  encode_ln_kernel<<<1024,256,0,stream>>>(E,g1,bt1,realp,xnp);
  // hid[h] = gelu(xn @ W1[h] + bh1[h])
  gemm_mfma<1><<<dim3(64,2,8),256,0,stream>>>(xnp, W1T_hi, W1T_lo, bh1, nullptr, hid,
                                              4096,256,128, 0, (long)256*128, 256, (long)4096*256);
  // t[h] = hid[h] @ W2[h] + bh2[h]
  gemm_mfma<0><<<dim3(64,1,8),256,0,stream>>>(hid, W2T_hi, W2T_lo, bh2, nullptr, tbuf,
                                              4096,128,256, (long)4096*256, (long)128*256, 128, (long)4096*128);
  autocorr_kernel<<<2048,256,0,stream>>>(tbuf, sigb);
  gate_ln_kernel<<<8192,256,0,stream>>>(realp, sigb, g2, bt2, ybuf);
  // out = y @ Wo + bo + x
  gemm_mfma<2><<<dim3(64,8,1),256,0,stream>>>(ybuf, WoT_hi, WoT_lo, bo, x, out,
                                              4096,1024,1024, 0,0,0,0);
}